// Round 8
// baseline (2374.999 us; speedup 1.0000x reference)
//
#include <hip/hip_runtime.h>
#include <stdint.h>

#define NN 100000
#define NE 1600000
#define NG 1000
#define LDA 112   // fp32 row stride for xs/h: 448 B, 64B-aligned rows
#define LDH 112   // short row stride for split-bf16 h tables
#define CPB 1563  // cols per build block: 64 * 1563 = 100032 >= NN

typedef float f32x4 __attribute__((ext_vector_type(4)));
typedef short s16x8 __attribute__((ext_vector_type(8)));

__device__ __forceinline__ unsigned short f2bf(float f) {
    unsigned u = __builtin_bit_cast(unsigned, f);
    unsigned r = u + 0x7FFFu + ((u >> 16) & 1u);
    return (unsigned short)(r >> 16);
}
__device__ __forceinline__ float bf2f(unsigned short h) {
    unsigned u = ((unsigned)h) << 16;
    return __builtin_bit_cast(float, u);
}

// ---- CSR build, ownership-partitioned: no global atomics, no write scatter ----
// Sweep 1: block b owns cols [b*CPB, (b+1)*CPB); LDS histogram of its range.
__global__ __launch_bounds__(1024) void k_build1(const int* __restrict__ col,
                                                 int* __restrict__ degcnt,
                                                 float* __restrict__ dinv,
                                                 int* __restrict__ bsum) {
    __shared__ int hist[CPB];
    __shared__ int p[1024];
    int t = threadIdx.x, b = blockIdx.x;
    int c0 = b * CPB;
    for (int i = t; i < CPB; i += 1024) hist[i] = 0;
    __syncthreads();
    for (int e = t; e < NE; e += 1024) {
        int c = col[e];
        unsigned rel = (unsigned)(c - c0);
        if (rel < CPB) atomicAdd(&hist[rel], 1);
    }
    __syncthreads();
    int loc = 0;
    for (int i = t; i < CPB; i += 1024) {
        int c = c0 + i;
        if (c < NN) {
            int d = hist[i];
            degcnt[c] = d;
            dinv[c] = 1.0f / sqrtf((float)d + 2.0f);
            loc += d;
        }
    }
    p[t] = loc; __syncthreads();
    for (int o = 512; o > 0; o >>= 1) {
        if (t < o) p[t] += p[t + o];
        __syncthreads();
    }
    if (t == 0) bsum[b] = p[0];
}

// tiny serial scan of 64 block totals
__global__ void k_scanB(const int* __restrict__ bsum, int* __restrict__ bbase,
                        int* __restrict__ indptr) {
    if (threadIdx.x == 0) {
        int acc = 0;
        for (int i = 0; i < 64; i++) { bbase[i] = acc; acc += bsum[i]; }
        indptr[NN] = NE;
    }
}

// Sweep 2: LDS scan of owned degrees -> indptr (coalesced); place edges via LDS
// fill counters into this block's private esrc window (single-XCD L2 absorbs).
__global__ __launch_bounds__(1024) void k_build2(const int* __restrict__ row,
                                                 const int* __restrict__ col,
                                                 const int* __restrict__ degcnt,
                                                 const int* __restrict__ bbase,
                                                 int* __restrict__ indptr,
                                                 int* __restrict__ esrc) {
    __shared__ int sc[2048];
    __shared__ int p[1024];
    __shared__ int lfill[CPB];
    int t = threadIdx.x, b = blockIdx.x;
    int c0 = b * CPB;
    int i0 = 2 * t, i1 = 2 * t + 1;
    int a0 = 0, a1 = 0;
    if (i0 < CPB && c0 + i0 < NN) a0 = degcnt[c0 + i0];
    if (i1 < CPB && c0 + i1 < NN) a1 = degcnt[c0 + i1];
    int s = a0 + a1;
    p[t] = s; __syncthreads();
    for (int o = 1; o < 1024; o <<= 1) {
        int x = (t >= o) ? p[t - o] : 0;
        __syncthreads();
        p[t] += x;
        __syncthreads();
    }
    int excl = p[t] - s;
    sc[i0] = excl;
    if (i1 < 2048) sc[i1] = excl + a0;
    int base = bbase[b];
    if (i0 < CPB) {
        if (c0 + i0 < NN) indptr[c0 + i0] = base + sc[i0];
        lfill[i0] = 0;
    }
    if (i1 < CPB) {
        if (c0 + i1 < NN) indptr[c0 + i1] = base + sc[i1];
        lfill[i1] = 0;
    }
    __syncthreads();
    for (int e = t; e < NE; e += 1024) {
        int c = col[e];
        unsigned rel = (unsigned)(c - c0);
        if (rel < CPB) {
            int pos = base + sc[rel] + atomicAdd(&lfill[rel], 1);
            esrc[pos] = row[e];
        }
    }
}

// batch is sorted: graph starts via boundary detection (no atomics, no scan)
__global__ void k_gbounds(const int* __restrict__ batch, int* __restrict__ gstart) {
    int i = blockIdx.x * 256 + threadIdx.x;
    if (i >= NN) return;
    int b = batch[i];
    int pb = (i == 0) ? -1 : batch[i - 1];
    for (int g = pb + 1; g <= b; g++) gstart[g] = i;
    if (i == NN - 1) {
        for (int g = b + 1; g <= NG; g++) gstart[g] = NN;
    }
}

// ----- all 5 weight conversions in one launch: Wt_{hi,lo}[112][KCP], zero-padded -----
__global__ void k_convWall(const float* __restrict__ W1, unsigned short* __restrict__ w1h, unsigned short* __restrict__ w1l,
                           const float* __restrict__ W2, unsigned short* __restrict__ w2h, unsigned short* __restrict__ w2l,
                           const float* __restrict__ W3, unsigned short* __restrict__ w3h, unsigned short* __restrict__ w3l,
                           const float* __restrict__ W4, unsigned short* __restrict__ w4h, unsigned short* __restrict__ w4l,
                           const float* __restrict__ W5, unsigned short* __restrict__ w5h, unsigned short* __restrict__ w5l) {
    int b = blockIdx.x, t = threadIdx.x;
    const float* W; unsigned short *Wh, *Wl; int K, KCP, idx;
    if (b < 168) {            // layer 1: 112*384 = 43008 = 168 blocks
        W = W1; Wh = w1h; Wl = w1l; K = 336; KCP = 384; idx = b * 256 + t;
    } else {                  // layers 2..5: 112*128 = 14336 = 56 blocks each
        int li = (b - 168) / 56;
        int lb = (b - 168) % 56;
        const float* Ws[4] = {W2, W3, W4, W5};
        unsigned short* Whs[4] = {w2h, w3h, w4h, w5h};
        unsigned short* Wls[4] = {w2l, w3l, w4l, w5l};
        W = Ws[li]; Wh = Whs[li]; Wl = Wls[li]; K = 100; KCP = 128; idx = lb * 256 + t;
    }
    int n = idx / KCP, k = idx - n * KCP;
    float v = (n < 100 && k < K) ? W[k * 100 + n] : 0.f;
    unsigned short hi = f2bf(v);
    Wh[idx] = hi;
    Wl[idx] = f2bf(v - bf2f(hi));
}

// ---- split-bf16 MFMA GEMM (fp32 A input, layer 1): xs = dinv * (A @ W) ----
__global__ __launch_bounds__(256) void k_gemm3(const float* __restrict__ A,
                                               const unsigned short* __restrict__ Wthi,
                                               const unsigned short* __restrict__ Wtlo,
                                               const float* __restrict__ dinv,
                                               float* __restrict__ out,
                                               int M, int K, int KCP, int lda) {
    __shared__ float As[64 * 68];
    __shared__ __align__(16) unsigned short Hs[112 * 72];
    __shared__ __align__(16) unsigned short Ls[112 * 72];
    int t = threadIdx.x;
    int lane = t & 63;
    int wv = t >> 6;
    int l15 = lane & 15, quad = lane >> 4;
    int rowbase = blockIdx.x * 64;

    f32x4 acc[7];
#pragma unroll
    for (int i = 0; i < 7; i++)
#pragma unroll
        for (int r = 0; r < 4; r++) acc[i][r] = 0.f;

    for (int k0 = 0; k0 < KCP; k0 += 64) {
        __syncthreads();
#pragma unroll
        for (int j = 0; j < 4; j++) {
            int e = t + j * 256;
            int r = e >> 4;
            int c4 = (e & 15) * 4;
            int gr = rowbase + r, gk = k0 + c4;
            float4 v = make_float4(0.f, 0.f, 0.f, 0.f);
            if (gr < M && gk < K) v = *(const float4*)(A + (size_t)gr * lda + gk);
            *(float4*)(&As[r * 68 + c4]) = v;
        }
#pragma unroll
        for (int j = 0; j < 7; j++) {
            int e = t + j * 256;
            int n = e >> 4;
            int c = (e & 15) * 4;
            size_t g = (size_t)n * KCP + k0 + c;
            *(uint2*)(&Hs[n * 72 + c]) = *(const uint2*)(Wthi + g);
            *(uint2*)(&Ls[n * 72 + c]) = *(const uint2*)(Wtlo + g);
        }
        __syncthreads();
#pragma unroll
        for (int ks = 0; ks < 2; ks++) {
            int arow = wv * 16 + l15;
            const float* ap = &As[arow * 68 + ks * 32 + quad * 8];
            float4 a0 = *(const float4*)ap;
            float4 a1 = *(const float4*)(ap + 4);
            float af[8] = {a0.x, a0.y, a0.z, a0.w, a1.x, a1.y, a1.z, a1.w};
            s16x8 ahi, alo;
#pragma unroll
            for (int j = 0; j < 8; j++) {
                unsigned short h = f2bf(af[j]);
                ahi[j] = (short)h;
                alo[j] = (short)f2bf(af[j] - bf2f(h));
            }
            int koff = ks * 32 + quad * 8;
#pragma unroll
            for (int tt = 0; tt < 7; tt++) {
                int nrow = tt * 16 + l15;
                s16x8 bhi = *(const s16x8*)(&Hs[nrow * 72 + koff]);
                s16x8 blo = *(const s16x8*)(&Ls[nrow * 72 + koff]);
                acc[tt] = __builtin_amdgcn_mfma_f32_16x16x32_bf16(ahi, bhi, acc[tt], 0, 0, 0);
                acc[tt] = __builtin_amdgcn_mfma_f32_16x16x32_bf16(ahi, blo, acc[tt], 0, 0, 0);
                acc[tt] = __builtin_amdgcn_mfma_f32_16x16x32_bf16(alo, bhi, acc[tt], 0, 0, 0);
            }
        }
    }

    int gr0 = rowbase + wv * 16 + quad * 4;
    float dv[4];
#pragma unroll
    for (int reg = 0; reg < 4; reg++) dv[reg] = (gr0 + reg < M) ? dinv[gr0 + reg] : 0.f;
#pragma unroll
    for (int tt = 0; tt < 7; tt++) {
        int n = tt * 16 + l15;
#pragma unroll
        for (int reg = 0; reg < 4; reg++) {
            int gr = gr0 + reg;
            if (gr < M) out[(size_t)gr * LDA + n] = dv[reg] * acc[tt][reg];
        }
    }
}

// ---- split-bf16 MFMA GEMM (split-bf16 A tables in, layers 2-5): xs = dinv*(h @ W) ----
__global__ __launch_bounds__(256) void k_gemm3s(const unsigned short* __restrict__ hhi,
                                                const unsigned short* __restrict__ hlo,
                                                const unsigned short* __restrict__ Wthi,
                                                const unsigned short* __restrict__ Wtlo,
                                                const float* __restrict__ dinv,
                                                float* __restrict__ out) {
    __shared__ __align__(16) unsigned short Ahi[64 * 72];
    __shared__ __align__(16) unsigned short Alo[64 * 72];
    __shared__ __align__(16) unsigned short Hs[112 * 72];
    __shared__ __align__(16) unsigned short Ls[112 * 72];
    int t = threadIdx.x;
    int lane = t & 63;
    int wv = t >> 6;
    int l15 = lane & 15, quad = lane >> 4;
    int rowbase = blockIdx.x * 64;

    f32x4 acc[7];
#pragma unroll
    for (int i = 0; i < 7; i++)
#pragma unroll
        for (int r = 0; r < 4; r++) acc[i][r] = 0.f;

    for (int k0 = 0; k0 < 128; k0 += 64) {
        __syncthreads();
#pragma unroll
        for (int j = 0; j < 2; j++) {
            int e = t + j * 256;           // 0..511
            int r = e >> 3;                // 0..63
            int c8 = (e & 7) * 8;          // 0..56
            int gr = rowbase + r;
            int gk = k0 + c8;
            uint4 vh = make_uint4(0, 0, 0, 0), vl = vh;
            if (gr < NN && gk + 8 <= LDH) {
                size_t g = (size_t)gr * LDH + gk;
                vh = *(const uint4*)(hhi + g);
                vl = *(const uint4*)(hlo + g);
            }
            *(uint4*)(&Ahi[r * 72 + c8]) = vh;
            *(uint4*)(&Alo[r * 72 + c8]) = vl;
        }
#pragma unroll
        for (int j = 0; j < 7; j++) {
            int e = t + j * 256;
            int n = e >> 4;
            int c = (e & 15) * 4;
            size_t g = (size_t)n * 128 + k0 + c;
            *(uint2*)(&Hs[n * 72 + c]) = *(const uint2*)(Wthi + g);
            *(uint2*)(&Ls[n * 72 + c]) = *(const uint2*)(Wtlo + g);
        }
        __syncthreads();
#pragma unroll
        for (int ks = 0; ks < 2; ks++) {
            int arow = wv * 16 + l15;
            int koff = ks * 32 + quad * 8;
            s16x8 ahi = *(const s16x8*)(&Ahi[arow * 72 + koff]);
            s16x8 alo = *(const s16x8*)(&Alo[arow * 72 + koff]);
#pragma unroll
            for (int tt = 0; tt < 7; tt++) {
                int nrow = tt * 16 + l15;
                s16x8 bhi = *(const s16x8*)(&Hs[nrow * 72 + koff]);
                s16x8 blo = *(const s16x8*)(&Ls[nrow * 72 + koff]);
                acc[tt] = __builtin_amdgcn_mfma_f32_16x16x32_bf16(ahi, bhi, acc[tt], 0, 0, 0);
                acc[tt] = __builtin_amdgcn_mfma_f32_16x16x32_bf16(ahi, blo, acc[tt], 0, 0, 0);
                acc[tt] = __builtin_amdgcn_mfma_f32_16x16x32_bf16(alo, bhi, acc[tt], 0, 0, 0);
            }
        }
    }

    int gr0 = rowbase + wv * 16 + quad * 4;
    float dv[4];
#pragma unroll
    for (int reg = 0; reg < 4; reg++) dv[reg] = (gr0 + reg < NN) ? dinv[gr0 + reg] : 0.f;
#pragma unroll
    for (int tt = 0; tt < 7; tt++) {
        int n = tt * 16 + l15;
#pragma unroll
        for (int reg = 0; reg < 4; reg++) {
            int gr = gr0 + reg;
            if (gr < NN) out[(size_t)gr * LDA + n] = dv[reg] * acc[tt][reg];
        }
    }
}

// ---- aggregation core (shared): returns (ax, ay) partial sums for this lane ----
__device__ __forceinline__ void agg_core(const float* __restrict__ xs,
                                         const int* __restrict__ esrc,
                                         int beg, int end, int lane, int col,
                                         float& ax, float& ay) {
    ax = 0.f; ay = 0.f;
    for (int c = beg; c < end; c += 64) {
        int m = min(64, end - c);
        int se = 0;
        if (lane < m) se = esrc[c + lane];
        int j = 0;
        for (; j + 16 <= m; j += 16) {
            float2 v[16];
#pragma unroll
            for (int u = 0; u < 16; u++) {
                int s = __builtin_amdgcn_readlane(se, j + u);
                v[u] = *(const float2*)(xs + (size_t)s * LDA + col);
            }
#pragma unroll
            for (int u = 0; u < 16; u++) { ax += v[u].x; ay += v[u].y; }
        }
        for (; j + 8 <= m; j += 8) {
            float2 v[8];
#pragma unroll
            for (int u = 0; u < 8; u++) {
                int s = __builtin_amdgcn_readlane(se, j + u);
                v[u] = *(const float2*)(xs + (size_t)s * LDA + col);
            }
#pragma unroll
            for (int u = 0; u < 8; u++) { ax += v[u].x; ay += v[u].y; }
        }
        for (; j + 4 <= m; j += 4) {
            float2 v[4];
#pragma unroll
            for (int u = 0; u < 4; u++) {
                int s = __builtin_amdgcn_readlane(se, j + u);
                v[u] = *(const float2*)(xs + (size_t)s * LDA + col);
            }
#pragma unroll
            for (int u = 0; u < 4; u++) { ax += v[u].x; ay += v[u].y; }
        }
        for (; j < m; j++) {
            int s = __builtin_amdgcn_readlane(se, j);
            float2 v = *(const float2*)(xs + (size_t)s * LDA + col);
            ax += v.x; ay += v.y;
        }
    }
}

// ---- agg with split-bf16 epilogue (layers 1-4): writes hhi/hlo tables ----
__global__ __launch_bounds__(256) void k_aggS(const float* __restrict__ xs,
                                              const int* __restrict__ indptr,
                                              const int* __restrict__ esrc,
                                              const float* __restrict__ dinv,
                                              const float* __restrict__ bias,
                                              unsigned short* __restrict__ hhi,
                                              unsigned short* __restrict__ hlo) {
    int wave = threadIdx.x >> 6;
    int lane = threadIdx.x & 63;
    int n = blockIdx.x * 4 + wave;
    if (n >= NN) return;
    int beg = indptr[n], end = indptr[n + 1];
    int col = (lane < 50) ? lane * 2 : 0;
    float ax, ay;
    agg_core(xs, esrc, beg, end, lane, col, ax, ay);
    if (lane < 50) {
        float di = dinv[n];
        float2 xv = *(const float2*)(xs + (size_t)n * LDA + col);
        float2 bv = *(const float2*)(bias + lane * 2);
        float hx = fmaxf(di * (ax + 2.f * xv.x) + bv.x, 0.f);
        float hy = fmaxf(di * (ay + 2.f * xv.y) + bv.y, 0.f);
        unsigned short xh = f2bf(hx), yh = f2bf(hy);
        *(ushort2*)(hhi + (size_t)n * LDH + col) = make_ushort2(xh, yh);
        *(ushort2*)(hlo + (size_t)n * LDH + col) =
            make_ushort2(f2bf(hx - bf2f(xh)), f2bf(hy - bf2f(yh)));
    } else if (lane < 56) {
        int pc = 100 + (lane - 50) * 2;
        *(ushort2*)(hhi + (size_t)n * LDH + pc) = make_ushort2(0, 0);
        *(ushort2*)(hlo + (size_t)n * LDH + pc) = make_ushort2(0, 0);
    }
}

// ---- agg with fp32 epilogue (layer 5): writes h for pooling ----
__global__ __launch_bounds__(256) void k_agg(const float* __restrict__ xs,
                                             const int* __restrict__ indptr,
                                             const int* __restrict__ esrc,
                                             const float* __restrict__ dinv,
                                             const float* __restrict__ bias,
                                             float* __restrict__ hout) {
    int wave = threadIdx.x >> 6;
    int lane = threadIdx.x & 63;
    int n = blockIdx.x * 4 + wave;
    if (n >= NN) return;
    int beg = indptr[n], end = indptr[n + 1];
    int col = (lane < 50) ? lane * 2 : 0;
    float ax, ay;
    agg_core(xs, esrc, beg, end, lane, col, ax, ay);
    if (lane < 50) {
        float di = dinv[n];
        float2 xv = *(const float2*)(xs + (size_t)n * LDA + col);
        float2 bv = *(const float2*)(bias + lane * 2);
        float2 r;
        r.x = fmaxf(di * (ax + 2.f * xv.x) + bv.x, 0.f);
        r.y = fmaxf(di * (ay + 2.f * xv.y) + bv.y, 0.f);
        *(float2*)(hout + (size_t)n * LDA + col) = r;
    }
}

// ---------------- pooling (8-way ILP over nodes) ----------------
__global__ __launch_bounds__(128) void k_pool(const float* __restrict__ h,
                                              const int* __restrict__ gstart,
                                              float* __restrict__ pooled) {
    int g = blockIdx.x, t = threadIdx.x;
    if (t >= 100) return;
    int st = gstart[g];
    int cnt = gstart[g + 1] - st;
    float s0 = 0.f, s1 = 0.f, s2 = 0.f, s3 = 0.f;
    float s4 = 0.f, s5 = 0.f, s6 = 0.f, s7 = 0.f;
    int i = 0;
    for (; i + 8 <= cnt; i += 8) {
        s0 += h[(size_t)(st + i) * LDA + t];
        s1 += h[(size_t)(st + i + 1) * LDA + t];
        s2 += h[(size_t)(st + i + 2) * LDA + t];
        s3 += h[(size_t)(st + i + 3) * LDA + t];
        s4 += h[(size_t)(st + i + 4) * LDA + t];
        s5 += h[(size_t)(st + i + 5) * LDA + t];
        s6 += h[(size_t)(st + i + 6) * LDA + t];
        s7 += h[(size_t)(st + i + 7) * LDA + t];
    }
    for (; i < cnt; i++) s0 += h[(size_t)(st + i) * LDA + t];
    float s = ((s0 + s1) + (s2 + s3)) + ((s4 + s5) + (s6 + s7));
    pooled[g * 100 + t] = s / (float)(cnt > 0 ? cnt : 1);
}

// ---------------- MLP head (fused 3 layers, one block per graph) ----------------
__global__ void k_mlp(const float* __restrict__ pooled,
                      const float* __restrict__ Wl1, const float* __restrict__ bl1,
                      const float* __restrict__ Wl2, const float* __restrict__ bl2,
                      const float* __restrict__ Wl3, const float* __restrict__ bl3,
                      float* __restrict__ out) {
    __shared__ float p[100], q[100];
    int g = blockIdx.x, t = threadIdx.x;
    if (t < 100) p[t] = pooled[g * 100 + t];
    __syncthreads();
    float s1 = 0.f;
    if (t < 100) {
        s1 = bl1[t];
        for (int k = 0; k < 100; k++) s1 += p[k] * Wl1[k * 100 + t];
        s1 = fmaxf(s1, 0.f);
    }
    __syncthreads();
    if (t < 100) q[t] = s1;
    __syncthreads();
    float s2 = 0.f;
    if (t < 100) {
        s2 = bl2[t];
        for (int k = 0; k < 100; k++) s2 += q[k] * Wl2[k * 100 + t];
        s2 = fmaxf(s2, 0.f);
    }
    __syncthreads();
    if (t < 100) p[t] = s2;
    __syncthreads();
    if (t < 29) {
        float s3 = bl3[t];
        for (int k = 0; k < 100; k++) s3 += p[k] * Wl3[k * 29 + t];
        out[g * 29 + t] = s3;
    }
}

// ---------------- launch ----------------
extern "C" void kernel_launch(void* const* d_in, const int* in_sizes, int n_in,
                              void* d_out, int out_size, void* d_ws, size_t ws_size,
                              hipStream_t stream) {
    const float* x     = (const float*)d_in[0];
    const int*   ei    = (const int*)d_in[1];
    const int*   batch = (const int*)d_in[2];
    const float* W1 = (const float*)d_in[3];  const float* b1 = (const float*)d_in[4];
    const float* W2 = (const float*)d_in[5];  const float* b2 = (const float*)d_in[6];
    const float* W3 = (const float*)d_in[7];  const float* b3 = (const float*)d_in[8];
    const float* W4 = (const float*)d_in[9];  const float* b4 = (const float*)d_in[10];
    const float* W5 = (const float*)d_in[11]; const float* b5 = (const float*)d_in[12];
    const float* Wl1 = (const float*)d_in[13]; const float* bl1 = (const float*)d_in[14];
    const float* Wl2 = (const float*)d_in[15]; const float* bl2 = (const float*)d_in[16];
    const float* Wl3 = (const float*)d_in[17]; const float* bl3 = (const float*)d_in[18];
    float* out = (float*)d_out;

    const int* row = ei;
    const int* col = ei + NE;

    uintptr_t base = (uintptr_t)d_ws;
    auto alloc = [&](size_t bytes) -> void* {
        void* p = (void*)base;
        base += (bytes + 255) & ~(size_t)255;
        return p;
    };
    int*   degcnt = (int*)alloc(NN * 4);
    float* dinv   = (float*)alloc(NN * 4);
    int*   indptr = (int*)alloc((NN + 1) * 4);
    int*   bsum   = (int*)alloc(64 * 4);
    int*   bbase  = (int*)alloc(64 * 4);
    int*   gstart = (int*)alloc((NG + 1) * 4);
    int*   esrc   = (int*)alloc((size_t)NE * 4);
    float* xs     = (float*)alloc((size_t)NN * LDA * 4);
    float* h      = (float*)alloc((size_t)NN * LDA * 4);
    unsigned short* hhi = (unsigned short*)alloc((size_t)NN * LDH * 2);
    unsigned short* hlo = (unsigned short*)alloc((size_t)NN * LDH * 2);
    float* pooled = (float*)alloc((size_t)NG * 100 * 4);
    unsigned short* w1hi = (unsigned short*)alloc((size_t)112 * 384 * 2);
    unsigned short* w1lo = (unsigned short*)alloc((size_t)112 * 384 * 2);
    unsigned short* w2hi = (unsigned short*)alloc((size_t)112 * 128 * 2);
    unsigned short* w2lo = (unsigned short*)alloc((size_t)112 * 128 * 2);
    unsigned short* w3hi = (unsigned short*)alloc((size_t)112 * 128 * 2);
    unsigned short* w3lo = (unsigned short*)alloc((size_t)112 * 128 * 2);
    unsigned short* w4hi = (unsigned short*)alloc((size_t)112 * 128 * 2);
    unsigned short* w4lo = (unsigned short*)alloc((size_t)112 * 128 * 2);
    unsigned short* w5hi = (unsigned short*)alloc((size_t)112 * 128 * 2);
    unsigned short* w5lo = (unsigned short*)alloc((size_t)112 * 128 * 2);

    // CSR build: no global atomics, no memsets
    k_build1<<<64, 1024, 0, stream>>>(col, degcnt, dinv, bsum);
    k_scanB<<<1, 64, 0, stream>>>(bsum, bbase, indptr);
    k_build2<<<64, 1024, 0, stream>>>(row, col, degcnt, bbase, indptr, esrc);
    k_gbounds<<<(NN + 255) / 256, 256, 0, stream>>>(batch, gstart);
    k_convWall<<<392, 256, 0, stream>>>(W1, w1hi, w1lo, W2, w2hi, w2lo,
                                        W3, w3hi, w3lo, W4, w4hi, w4lo,
                                        W5, w5hi, w5lo);

    const int GEMM_GRID = (NN + 63) / 64;  // 1563
    const int AGG_GRID = (NN + 3) / 4;     // 25000

    k_gemm3<<<GEMM_GRID, 256, 0, stream>>>(x, w1hi, w1lo, dinv, xs, NN, 336, 384, 336);
    k_aggS<<<AGG_GRID, 256, 0, stream>>>(xs, indptr, esrc, dinv, b1, hhi, hlo);
    k_gemm3s<<<GEMM_GRID, 256, 0, stream>>>(hhi, hlo, w2hi, w2lo, dinv, xs);
    k_aggS<<<AGG_GRID, 256, 0, stream>>>(xs, indptr, esrc, dinv, b2, hhi, hlo);
    k_gemm3s<<<GEMM_GRID, 256, 0, stream>>>(hhi, hlo, w3hi, w3lo, dinv, xs);
    k_aggS<<<AGG_GRID, 256, 0, stream>>>(xs, indptr, esrc, dinv, b3, hhi, hlo);
    k_gemm3s<<<GEMM_GRID, 256, 0, stream>>>(hhi, hlo, w4hi, w4lo, dinv, xs);
    k_aggS<<<AGG_GRID, 256, 0, stream>>>(xs, indptr, esrc, dinv, b4, hhi, hlo);
    k_gemm3s<<<GEMM_GRID, 256, 0, stream>>>(hhi, hlo, w5hi, w5lo, dinv, xs);
    k_agg<<<AGG_GRID, 256, 0, stream>>>(xs, indptr, esrc, dinv, b5, h);

    k_pool<<<NG, 128, 0, stream>>>(h, gstart, pooled);
    k_mlp<<<NG, 128, 0, stream>>>(pooled, Wl1, bl1, Wl2, bl2, Wl3, bl3, out);
}

// Round 9
// 1155.810 us; speedup vs baseline: 2.0548x; 2.0548x over previous
//
#include <hip/hip_runtime.h>
#include <stdint.h>

#define NN 100000
#define NE 1600000
#define NG 1000
#define LDA 112   // fp32 row stride for xs/h: 448 B, 64B-aligned rows
#define LDH 112   // short row stride for split-bf16 h tables

typedef float f32x4 __attribute__((ext_vector_type(4)));
typedef short s16x8 __attribute__((ext_vector_type(8)));

__device__ __forceinline__ unsigned short f2bf(float f) {
    unsigned u = __builtin_bit_cast(unsigned, f);
    unsigned r = u + 0x7FFFu + ((u >> 16) & 1u);
    return (unsigned short)(r >> 16);
}
__device__ __forceinline__ float bf2f(unsigned short h) {
    unsigned u = ((unsigned)h) << 16;
    return __builtin_bit_cast(float, u);
}

// ---------------- degree ----------------
__global__ void k_deg(const int* __restrict__ col, int* __restrict__ degcnt) {
    int e = blockIdx.x * 256 + threadIdx.x;
    if (e < NE) atomicAdd(&degcnt[col[e]], 1);
}

// ---------------- prefix scans for CSR ----------------
__global__ void k_scan1(const int* __restrict__ cnt, int* __restrict__ csum) {
    __shared__ int s[256];
    int i = blockIdx.x * 256 + threadIdx.x;
    s[threadIdx.x] = (i < NN) ? cnt[i] : 0;
    __syncthreads();
    for (int o = 128; o > 0; o >>= 1) {
        if (threadIdx.x < o) s[threadIdx.x] += s[threadIdx.x + o];
        __syncthreads();
    }
    if (threadIdx.x == 0) csum[blockIdx.x] = s[0];
}

__global__ void k_scan2(const int* __restrict__ csum, int* __restrict__ csum2, int nb) {
    __shared__ int s[512];
    int t = threadIdx.x;
    int v = (t < nb) ? csum[t] : 0;
    s[t] = v; __syncthreads();
    for (int o = 1; o < 512; o <<= 1) {
        int x = (t >= o) ? s[t - o] : 0;
        __syncthreads();
        s[t] += x;
        __syncthreads();
    }
    if (t < nb) csum2[t] = s[t] - v;  // exclusive
}

// indptr + dinv in one pass
__global__ void k_scan3d(const int* __restrict__ cnt, const int* __restrict__ csum2,
                         int* __restrict__ indptr, float* __restrict__ dinv) {
    __shared__ int s[256];
    int t = threadIdx.x;
    int i = blockIdx.x * 256 + t;
    int v = (i < NN) ? cnt[i] : 0;
    s[t] = v; __syncthreads();
    for (int o = 1; o < 256; o <<= 1) {
        int x = (t >= o) ? s[t - o] : 0;
        __syncthreads();
        s[t] += x;
        __syncthreads();
    }
    if (i < NN) {
        indptr[i] = csum2[blockIdx.x] + s[t] - v;
        dinv[i] = 1.0f / sqrtf((float)v + 2.0f);
    }
    if (i == 0) indptr[NN] = NE;
}

__global__ void k_scatter(const int* __restrict__ row, const int* __restrict__ col,
                          const int* __restrict__ indptr,
                          int* __restrict__ fill, int* __restrict__ esrc) {
    int e = blockIdx.x * 256 + threadIdx.x;
    if (e >= NE) return;
    int r = row[e], c = col[e];
    int pos = indptr[c] + atomicAdd(&fill[c], 1);
    esrc[pos] = r;
}

// batch is sorted: graph starts via boundary detection (no atomics, no scan)
__global__ void k_gbounds(const int* __restrict__ batch, int* __restrict__ gstart) {
    int i = blockIdx.x * 256 + threadIdx.x;
    if (i >= NN) return;
    int b = batch[i];
    int pb = (i == 0) ? -1 : batch[i - 1];
    for (int g = pb + 1; g <= b; g++) gstart[g] = i;
    if (i == NN - 1) {
        for (int g = b + 1; g <= NG; g++) gstart[g] = NN;
    }
}

// ----- all 5 weight conversions in one launch: Wt_{hi,lo}[112][KCP], zero-padded -----
__global__ void k_convWall(const float* __restrict__ W1, unsigned short* __restrict__ w1h, unsigned short* __restrict__ w1l,
                           const float* __restrict__ W2, unsigned short* __restrict__ w2h, unsigned short* __restrict__ w2l,
                           const float* __restrict__ W3, unsigned short* __restrict__ w3h, unsigned short* __restrict__ w3l,
                           const float* __restrict__ W4, unsigned short* __restrict__ w4h, unsigned short* __restrict__ w4l,
                           const float* __restrict__ W5, unsigned short* __restrict__ w5h, unsigned short* __restrict__ w5l) {
    int b = blockIdx.x, t = threadIdx.x;
    const float* W; unsigned short *Wh, *Wl; int K, KCP, idx;
    if (b < 168) {            // layer 1: 112*384 = 43008 = 168 blocks
        W = W1; Wh = w1h; Wl = w1l; K = 336; KCP = 384; idx = b * 256 + t;
    } else {                  // layers 2..5: 112*128 = 14336 = 56 blocks each
        int li = (b - 168) / 56;
        int lb = (b - 168) % 56;
        const float* Ws[4] = {W2, W3, W4, W5};
        unsigned short* Whs[4] = {w2h, w3h, w4h, w5h};
        unsigned short* Wls[4] = {w2l, w3l, w4l, w5l};
        W = Ws[li]; Wh = Whs[li]; Wl = Wls[li]; K = 100; KCP = 128; idx = lb * 256 + t;
    }
    int n = idx / KCP, k = idx - n * KCP;
    float v = (n < 100 && k < K) ? W[k * 100 + n] : 0.f;
    unsigned short hi = f2bf(v);
    Wh[idx] = hi;
    Wl[idx] = f2bf(v - bf2f(hi));
}

// ---- split-bf16 MFMA GEMM (fp32 A input, layer 1): xs = dinv * (A @ W) ----
__global__ __launch_bounds__(256) void k_gemm3(const float* __restrict__ A,
                                               const unsigned short* __restrict__ Wthi,
                                               const unsigned short* __restrict__ Wtlo,
                                               const float* __restrict__ dinv,
                                               float* __restrict__ out,
                                               int M, int K, int KCP, int lda) {
    __shared__ float As[64 * 68];
    __shared__ __align__(16) unsigned short Hs[112 * 72];
    __shared__ __align__(16) unsigned short Ls[112 * 72];
    int t = threadIdx.x;
    int lane = t & 63;
    int wv = t >> 6;
    int l15 = lane & 15, quad = lane >> 4;
    int rowbase = blockIdx.x * 64;

    f32x4 acc[7];
#pragma unroll
    for (int i = 0; i < 7; i++)
#pragma unroll
        for (int r = 0; r < 4; r++) acc[i][r] = 0.f;

    for (int k0 = 0; k0 < KCP; k0 += 64) {
        __syncthreads();
#pragma unroll
        for (int j = 0; j < 4; j++) {
            int e = t + j * 256;
            int r = e >> 4;
            int c4 = (e & 15) * 4;
            int gr = rowbase + r, gk = k0 + c4;
            float4 v = make_float4(0.f, 0.f, 0.f, 0.f);
            if (gr < M && gk < K) v = *(const float4*)(A + (size_t)gr * lda + gk);
            *(float4*)(&As[r * 68 + c4]) = v;
        }
#pragma unroll
        for (int j = 0; j < 7; j++) {
            int e = t + j * 256;
            int n = e >> 4;
            int c = (e & 15) * 4;
            size_t g = (size_t)n * KCP + k0 + c;
            *(uint2*)(&Hs[n * 72 + c]) = *(const uint2*)(Wthi + g);
            *(uint2*)(&Ls[n * 72 + c]) = *(const uint2*)(Wtlo + g);
        }
        __syncthreads();
#pragma unroll
        for (int ks = 0; ks < 2; ks++) {
            int arow = wv * 16 + l15;
            const float* ap = &As[arow * 68 + ks * 32 + quad * 8];
            float4 a0 = *(const float4*)ap;
            float4 a1 = *(const float4*)(ap + 4);
            float af[8] = {a0.x, a0.y, a0.z, a0.w, a1.x, a1.y, a1.z, a1.w};
            s16x8 ahi, alo;
#pragma unroll
            for (int j = 0; j < 8; j++) {
                unsigned short h = f2bf(af[j]);
                ahi[j] = (short)h;
                alo[j] = (short)f2bf(af[j] - bf2f(h));
            }
            int koff = ks * 32 + quad * 8;
#pragma unroll
            for (int tt = 0; tt < 7; tt++) {
                int nrow = tt * 16 + l15;
                s16x8 bhi = *(const s16x8*)(&Hs[nrow * 72 + koff]);
                s16x8 blo = *(const s16x8*)(&Ls[nrow * 72 + koff]);
                acc[tt] = __builtin_amdgcn_mfma_f32_16x16x32_bf16(ahi, bhi, acc[tt], 0, 0, 0);
                acc[tt] = __builtin_amdgcn_mfma_f32_16x16x32_bf16(ahi, blo, acc[tt], 0, 0, 0);
                acc[tt] = __builtin_amdgcn_mfma_f32_16x16x32_bf16(alo, bhi, acc[tt], 0, 0, 0);
            }
        }
    }

    int gr0 = rowbase + wv * 16 + quad * 4;
    float dv[4];
#pragma unroll
    for (int reg = 0; reg < 4; reg++) dv[reg] = (gr0 + reg < M) ? dinv[gr0 + reg] : 0.f;
#pragma unroll
    for (int tt = 0; tt < 7; tt++) {
        int n = tt * 16 + l15;
#pragma unroll
        for (int reg = 0; reg < 4; reg++) {
            int gr = gr0 + reg;
            if (gr < M) out[(size_t)gr * LDA + n] = dv[reg] * acc[tt][reg];
        }
    }
}

// ---- split-bf16 MFMA GEMM (split-bf16 A tables in, layers 2-5): xs = dinv*(h @ W) ----
__global__ __launch_bounds__(256) void k_gemm3s(const unsigned short* __restrict__ hhi,
                                                const unsigned short* __restrict__ hlo,
                                                const unsigned short* __restrict__ Wthi,
                                                const unsigned short* __restrict__ Wtlo,
                                                const float* __restrict__ dinv,
                                                float* __restrict__ out) {
    __shared__ __align__(16) unsigned short Ahi[64 * 72];
    __shared__ __align__(16) unsigned short Alo[64 * 72];
    __shared__ __align__(16) unsigned short Hs[112 * 72];
    __shared__ __align__(16) unsigned short Ls[112 * 72];
    int t = threadIdx.x;
    int lane = t & 63;
    int wv = t >> 6;
    int l15 = lane & 15, quad = lane >> 4;
    int rowbase = blockIdx.x * 64;

    f32x4 acc[7];
#pragma unroll
    for (int i = 0; i < 7; i++)
#pragma unroll
        for (int r = 0; r < 4; r++) acc[i][r] = 0.f;

    for (int k0 = 0; k0 < 128; k0 += 64) {
        __syncthreads();
#pragma unroll
        for (int j = 0; j < 2; j++) {
            int e = t + j * 256;           // 0..511
            int r = e >> 3;                // 0..63
            int c8 = (e & 7) * 8;          // 0..56
            int gr = rowbase + r;
            int gk = k0 + c8;
            uint4 vh = make_uint4(0, 0, 0, 0), vl = vh;
            if (gr < NN && gk + 8 <= LDH) {
                size_t g = (size_t)gr * LDH + gk;
                vh = *(const uint4*)(hhi + g);
                vl = *(const uint4*)(hlo + g);
            }
            *(uint4*)(&Ahi[r * 72 + c8]) = vh;
            *(uint4*)(&Alo[r * 72 + c8]) = vl;
        }
#pragma unroll
        for (int j = 0; j < 7; j++) {
            int e = t + j * 256;
            int n = e >> 4;
            int c = (e & 15) * 4;
            size_t g = (size_t)n * 128 + k0 + c;
            *(uint2*)(&Hs[n * 72 + c]) = *(const uint2*)(Wthi + g);
            *(uint2*)(&Ls[n * 72 + c]) = *(const uint2*)(Wtlo + g);
        }
        __syncthreads();
#pragma unroll
        for (int ks = 0; ks < 2; ks++) {
            int arow = wv * 16 + l15;
            int koff = ks * 32 + quad * 8;
            s16x8 ahi = *(const s16x8*)(&Ahi[arow * 72 + koff]);
            s16x8 alo = *(const s16x8*)(&Alo[arow * 72 + koff]);
#pragma unroll
            for (int tt = 0; tt < 7; tt++) {
                int nrow = tt * 16 + l15;
                s16x8 bhi = *(const s16x8*)(&Hs[nrow * 72 + koff]);
                s16x8 blo = *(const s16x8*)(&Ls[nrow * 72 + koff]);
                acc[tt] = __builtin_amdgcn_mfma_f32_16x16x32_bf16(ahi, bhi, acc[tt], 0, 0, 0);
                acc[tt] = __builtin_amdgcn_mfma_f32_16x16x32_bf16(ahi, blo, acc[tt], 0, 0, 0);
                acc[tt] = __builtin_amdgcn_mfma_f32_16x16x32_bf16(alo, bhi, acc[tt], 0, 0, 0);
            }
        }
    }

    int gr0 = rowbase + wv * 16 + quad * 4;
    float dv[4];
#pragma unroll
    for (int reg = 0; reg < 4; reg++) dv[reg] = (gr0 + reg < NN) ? dinv[gr0 + reg] : 0.f;
#pragma unroll
    for (int tt = 0; tt < 7; tt++) {
        int n = tt * 16 + l15;
#pragma unroll
        for (int reg = 0; reg < 4; reg++) {
            int gr = gr0 + reg;
            if (gr < NN) out[(size_t)gr * LDA + n] = dv[reg] * acc[tt][reg];
        }
    }
}

// ---- aggregation core (shared): returns (ax, ay) partial sums for this lane ----
__device__ __forceinline__ void agg_core(const float* __restrict__ xs,
                                         const int* __restrict__ esrc,
                                         int beg, int end, int lane, int col,
                                         float& ax, float& ay) {
    ax = 0.f; ay = 0.f;
    for (int c = beg; c < end; c += 64) {
        int m = min(64, end - c);
        int se = 0;
        if (lane < m) se = esrc[c + lane];
        int j = 0;
        for (; j + 16 <= m; j += 16) {
            float2 v[16];
#pragma unroll
            for (int u = 0; u < 16; u++) {
                int s = __builtin_amdgcn_readlane(se, j + u);
                v[u] = *(const float2*)(xs + (size_t)s * LDA + col);
            }
#pragma unroll
            for (int u = 0; u < 16; u++) { ax += v[u].x; ay += v[u].y; }
        }
        for (; j + 8 <= m; j += 8) {
            float2 v[8];
#pragma unroll
            for (int u = 0; u < 8; u++) {
                int s = __builtin_amdgcn_readlane(se, j + u);
                v[u] = *(const float2*)(xs + (size_t)s * LDA + col);
            }
#pragma unroll
            for (int u = 0; u < 8; u++) { ax += v[u].x; ay += v[u].y; }
        }
        for (; j + 4 <= m; j += 4) {
            float2 v[4];
#pragma unroll
            for (int u = 0; u < 4; u++) {
                int s = __builtin_amdgcn_readlane(se, j + u);
                v[u] = *(const float2*)(xs + (size_t)s * LDA + col);
            }
#pragma unroll
            for (int u = 0; u < 4; u++) { ax += v[u].x; ay += v[u].y; }
        }
        for (; j < m; j++) {
            int s = __builtin_amdgcn_readlane(se, j);
            float2 v = *(const float2*)(xs + (size_t)s * LDA + col);
            ax += v.x; ay += v.y;
        }
    }
}

// ---- agg with split-bf16 epilogue (layers 1-4): writes hhi/hlo tables ----
__global__ __launch_bounds__(256) void k_aggS(const float* __restrict__ xs,
                                              const int* __restrict__ indptr,
                                              const int* __restrict__ esrc,
                                              const float* __restrict__ dinv,
                                              const float* __restrict__ bias,
                                              unsigned short* __restrict__ hhi,
                                              unsigned short* __restrict__ hlo) {
    int wave = threadIdx.x >> 6;
    int lane = threadIdx.x & 63;
    int n = blockIdx.x * 4 + wave;
    if (n >= NN) return;
    int beg = indptr[n], end = indptr[n + 1];
    int col = (lane < 50) ? lane * 2 : 0;
    float ax, ay;
    agg_core(xs, esrc, beg, end, lane, col, ax, ay);
    if (lane < 50) {
        float di = dinv[n];
        float2 xv = *(const float2*)(xs + (size_t)n * LDA + col);
        float2 bv = *(const float2*)(bias + lane * 2);
        float hx = fmaxf(di * (ax + 2.f * xv.x) + bv.x, 0.f);
        float hy = fmaxf(di * (ay + 2.f * xv.y) + bv.y, 0.f);
        unsigned short xh = f2bf(hx), yh = f2bf(hy);
        *(ushort2*)(hhi + (size_t)n * LDH + col) = make_ushort2(xh, yh);
        *(ushort2*)(hlo + (size_t)n * LDH + col) =
            make_ushort2(f2bf(hx - bf2f(xh)), f2bf(hy - bf2f(yh)));
    } else if (lane < 56) {
        int pc = 100 + (lane - 50) * 2;
        *(ushort2*)(hhi + (size_t)n * LDH + pc) = make_ushort2(0, 0);
        *(ushort2*)(hlo + (size_t)n * LDH + pc) = make_ushort2(0, 0);
    }
}

// ---- agg with fp32 epilogue (layer 5): writes h for pooling ----
__global__ __launch_bounds__(256) void k_agg(const float* __restrict__ xs,
                                             const int* __restrict__ indptr,
                                             const int* __restrict__ esrc,
                                             const float* __restrict__ dinv,
                                             const float* __restrict__ bias,
                                             float* __restrict__ hout) {
    int wave = threadIdx.x >> 6;
    int lane = threadIdx.x & 63;
    int n = blockIdx.x * 4 + wave;
    if (n >= NN) return;
    int beg = indptr[n], end = indptr[n + 1];
    int col = (lane < 50) ? lane * 2 : 0;
    float ax, ay;
    agg_core(xs, esrc, beg, end, lane, col, ax, ay);
    if (lane < 50) {
        float di = dinv[n];
        float2 xv = *(const float2*)(xs + (size_t)n * LDA + col);
        float2 bv = *(const float2*)(bias + lane * 2);
        float2 r;
        r.x = fmaxf(di * (ax + 2.f * xv.x) + bv.x, 0.f);
        r.y = fmaxf(di * (ay + 2.f * xv.y) + bv.y, 0.f);
        *(float2*)(hout + (size_t)n * LDA + col) = r;
    }
}

// ---------------- pooling (8-way ILP over nodes) ----------------
__global__ __launch_bounds__(128) void k_pool(const float* __restrict__ h,
                                              const int* __restrict__ gstart,
                                              float* __restrict__ pooled) {
    int g = blockIdx.x, t = threadIdx.x;
    if (t >= 100) return;
    int st = gstart[g];
    int cnt = gstart[g + 1] - st;
    float s0 = 0.f, s1 = 0.f, s2 = 0.f, s3 = 0.f;
    float s4 = 0.f, s5 = 0.f, s6 = 0.f, s7 = 0.f;
    int i = 0;
    for (; i + 8 <= cnt; i += 8) {
        s0 += h[(size_t)(st + i) * LDA + t];
        s1 += h[(size_t)(st + i + 1) * LDA + t];
        s2 += h[(size_t)(st + i + 2) * LDA + t];
        s3 += h[(size_t)(st + i + 3) * LDA + t];
        s4 += h[(size_t)(st + i + 4) * LDA + t];
        s5 += h[(size_t)(st + i + 5) * LDA + t];
        s6 += h[(size_t)(st + i + 6) * LDA + t];
        s7 += h[(size_t)(st + i + 7) * LDA + t];
    }
    for (; i < cnt; i++) s0 += h[(size_t)(st + i) * LDA + t];
    float s = ((s0 + s1) + (s2 + s3)) + ((s4 + s5) + (s6 + s7));
    pooled[g * 100 + t] = s / (float)(cnt > 0 ? cnt : 1);
}

// ---------------- MLP head (fused 3 layers, one block per graph) ----------------
__global__ void k_mlp(const float* __restrict__ pooled,
                      const float* __restrict__ Wl1, const float* __restrict__ bl1,
                      const float* __restrict__ Wl2, const float* __restrict__ bl2,
                      const float* __restrict__ Wl3, const float* __restrict__ bl3,
                      float* __restrict__ out) {
    __shared__ float p[100], q[100];
    int g = blockIdx.x, t = threadIdx.x;
    if (t < 100) p[t] = pooled[g * 100 + t];
    __syncthreads();
    float s1 = 0.f;
    if (t < 100) {
        s1 = bl1[t];
        for (int k = 0; k < 100; k++) s1 += p[k] * Wl1[k * 100 + t];
        s1 = fmaxf(s1, 0.f);
    }
    __syncthreads();
    if (t < 100) q[t] = s1;
    __syncthreads();
    float s2 = 0.f;
    if (t < 100) {
        s2 = bl2[t];
        for (int k = 0; k < 100; k++) s2 += q[k] * Wl2[k * 100 + t];
        s2 = fmaxf(s2, 0.f);
    }
    __syncthreads();
    if (t < 100) p[t] = s2;
    __syncthreads();
    if (t < 29) {
        float s3 = bl3[t];
        for (int k = 0; k < 100; k++) s3 += p[k] * Wl3[k * 29 + t];
        out[g * 29 + t] = s3;
    }
}

// ---------------- launch ----------------
extern "C" void kernel_launch(void* const* d_in, const int* in_sizes, int n_in,
                              void* d_out, int out_size, void* d_ws, size_t ws_size,
                              hipStream_t stream) {
    const float* x     = (const float*)d_in[0];
    const int*   ei    = (const int*)d_in[1];
    const int*   batch = (const int*)d_in[2];
    const float* W1 = (const float*)d_in[3];  const float* b1 = (const float*)d_in[4];
    const float* W2 = (const float*)d_in[5];  const float* b2 = (const float*)d_in[6];
    const float* W3 = (const float*)d_in[7];  const float* b3 = (const float*)d_in[8];
    const float* W4 = (const float*)d_in[9];  const float* b4 = (const float*)d_in[10];
    const float* W5 = (const float*)d_in[11]; const float* b5 = (const float*)d_in[12];
    const float* Wl1 = (const float*)d_in[13]; const float* bl1 = (const float*)d_in[14];
    const float* Wl2 = (const float*)d_in[15]; const float* bl2 = (const float*)d_in[16];
    const float* Wl3 = (const float*)d_in[17]; const float* bl3 = (const float*)d_in[18];
    float* out = (float*)d_out;

    const int* row = ei;
    const int* col = ei + NE;

    uintptr_t base = (uintptr_t)d_ws;
    auto alloc = [&](size_t bytes) -> void* {
        void* p = (void*)base;
        base += (bytes + 255) & ~(size_t)255;
        return p;
    };
    // contiguous atomic-counter region -> single memset
    int*   cnts   = (int*)alloc((size_t)(2 * NN) * 4);
    int*   degcnt = cnts;
    int*   fill   = cnts + NN;
    float* dinv   = (float*)alloc(NN * 4);
    int*   indptr = (int*)alloc((NN + 1) * 4);
    int*   csum   = (int*)alloc(512 * 4);
    int*   csum2  = (int*)alloc(512 * 4);
    int*   gstart = (int*)alloc((NG + 1) * 4);
    int*   esrc   = (int*)alloc((size_t)NE * 4);
    float* xs     = (float*)alloc((size_t)NN * LDA * 4);
    float* h      = (float*)alloc((size_t)NN * LDA * 4);
    unsigned short* hhi = (unsigned short*)alloc((size_t)NN * LDH * 2);
    unsigned short* hlo = (unsigned short*)alloc((size_t)NN * LDH * 2);
    float* pooled = (float*)alloc((size_t)NG * 100 * 4);
    unsigned short* w1hi = (unsigned short*)alloc((size_t)112 * 384 * 2);
    unsigned short* w1lo = (unsigned short*)alloc((size_t)112 * 384 * 2);
    unsigned short* w2hi = (unsigned short*)alloc((size_t)112 * 128 * 2);
    unsigned short* w2lo = (unsigned short*)alloc((size_t)112 * 128 * 2);
    unsigned short* w3hi = (unsigned short*)alloc((size_t)112 * 128 * 2);
    unsigned short* w3lo = (unsigned short*)alloc((size_t)112 * 128 * 2);
    unsigned short* w4hi = (unsigned short*)alloc((size_t)112 * 128 * 2);
    unsigned short* w4lo = (unsigned short*)alloc((size_t)112 * 128 * 2);
    unsigned short* w5hi = (unsigned short*)alloc((size_t)112 * 128 * 2);
    unsigned short* w5lo = (unsigned short*)alloc((size_t)112 * 128 * 2);

    hipMemsetAsync(cnts, 0, (size_t)(2 * NN) * 4, stream);

    const int NB = (NN + 255) / 256;  // 391
    k_deg<<<(NE + 255) / 256, 256, 0, stream>>>(col, degcnt);
    k_scan1<<<NB, 256, 0, stream>>>(degcnt, csum);
    k_scan2<<<1, 512, 0, stream>>>(csum, csum2, NB);
    k_scan3d<<<NB, 256, 0, stream>>>(degcnt, csum2, indptr, dinv);
    k_scatter<<<(NE + 255) / 256, 256, 0, stream>>>(row, col, indptr, fill, esrc);
    k_gbounds<<<NB, 256, 0, stream>>>(batch, gstart);
    k_convWall<<<392, 256, 0, stream>>>(W1, w1hi, w1lo, W2, w2hi, w2lo,
                                        W3, w3hi, w3lo, W4, w4hi, w4lo,
                                        W5, w5hi, w5lo);

    const int GEMM_GRID = (NN + 63) / 64;  // 1563
    const int AGG_GRID = (NN + 3) / 4;     // 25000

    k_gemm3<<<GEMM_GRID, 256, 0, stream>>>(x, w1hi, w1lo, dinv, xs, NN, 336, 384, 336);
    k_aggS<<<AGG_GRID, 256, 0, stream>>>(xs, indptr, esrc, dinv, b1, hhi, hlo);
    k_gemm3s<<<GEMM_GRID, 256, 0, stream>>>(hhi, hlo, w2hi, w2lo, dinv, xs);
    k_aggS<<<AGG_GRID, 256, 0, stream>>>(xs, indptr, esrc, dinv, b2, hhi, hlo);
    k_gemm3s<<<GEMM_GRID, 256, 0, stream>>>(hhi, hlo, w3hi, w3lo, dinv, xs);
    k_aggS<<<AGG_GRID, 256, 0, stream>>>(xs, indptr, esrc, dinv, b3, hhi, hlo);
    k_gemm3s<<<GEMM_GRID, 256, 0, stream>>>(hhi, hlo, w4hi, w4lo, dinv, xs);
    k_aggS<<<AGG_GRID, 256, 0, stream>>>(xs, indptr, esrc, dinv, b4, hhi, hlo);
    k_gemm3s<<<GEMM_GRID, 256, 0, stream>>>(hhi, hlo, w5hi, w5lo, dinv, xs);
    k_agg<<<AGG_GRID, 256, 0, stream>>>(xs, indptr, esrc, dinv, b5, h);

    k_pool<<<NG, 128, 0, stream>>>(h, gstart, pooled);
    k_mlp<<<NG, 128, 0, stream>>>(pooled, Wl1, bl1, Wl2, bl2, Wl3, bl3, out);
}

// Round 10
// 877.573 us; speedup vs baseline: 2.7063x; 1.3171x over previous
//
#include <hip/hip_runtime.h>
#include <hip/hip_fp16.h>
#include <stdint.h>

#define NN 100000
#define NE 1600000
#define NG 1000
#define LDA 112   // fp32 row stride for h (pooling input): 448 B
#define LDH 112   // short row stride for split-bf16 h tables (GEMM A input)
#define LDX 128   // half row stride for fp16 xs gather table: 256 B, 64B-aligned

typedef float f32x4 __attribute__((ext_vector_type(4)));
typedef short s16x8 __attribute__((ext_vector_type(8)));

__device__ __forceinline__ unsigned short f2bf(float f) {
    unsigned u = __builtin_bit_cast(unsigned, f);
    unsigned r = u + 0x7FFFu + ((u >> 16) & 1u);
    return (unsigned short)(r >> 16);
}
__device__ __forceinline__ float bf2f(unsigned short h) {
    unsigned u = ((unsigned)h) << 16;
    return __builtin_bit_cast(float, u);
}

// ---------------- degree ----------------
__global__ void k_deg(const int* __restrict__ col, int* __restrict__ degcnt) {
    int e = blockIdx.x * 256 + threadIdx.x;
    if (e < NE) atomicAdd(&degcnt[col[e]], 1);
}

// ---------------- prefix scans for CSR ----------------
__global__ void k_scan1(const int* __restrict__ cnt, int* __restrict__ csum) {
    __shared__ int s[256];
    int i = blockIdx.x * 256 + threadIdx.x;
    s[threadIdx.x] = (i < NN) ? cnt[i] : 0;
    __syncthreads();
    for (int o = 128; o > 0; o >>= 1) {
        if (threadIdx.x < o) s[threadIdx.x] += s[threadIdx.x + o];
        __syncthreads();
    }
    if (threadIdx.x == 0) csum[blockIdx.x] = s[0];
}

__global__ void k_scan2(const int* __restrict__ csum, int* __restrict__ csum2, int nb) {
    __shared__ int s[512];
    int t = threadIdx.x;
    int v = (t < nb) ? csum[t] : 0;
    s[t] = v; __syncthreads();
    for (int o = 1; o < 512; o <<= 1) {
        int x = (t >= o) ? s[t - o] : 0;
        __syncthreads();
        s[t] += x;
        __syncthreads();
    }
    if (t < nb) csum2[t] = s[t] - v;  // exclusive
}

// indptr + dinv in one pass
__global__ void k_scan3d(const int* __restrict__ cnt, const int* __restrict__ csum2,
                         int* __restrict__ indptr, float* __restrict__ dinv) {
    __shared__ int s[256];
    int t = threadIdx.x;
    int i = blockIdx.x * 256 + t;
    int v = (i < NN) ? cnt[i] : 0;
    s[t] = v; __syncthreads();
    for (int o = 1; o < 256; o <<= 1) {
        int x = (t >= o) ? s[t - o] : 0;
        __syncthreads();
        s[t] += x;
        __syncthreads();
    }
    if (i < NN) {
        indptr[i] = csum2[blockIdx.x] + s[t] - v;
        dinv[i] = 1.0f / sqrtf((float)v + 2.0f);
    }
    if (i == 0) indptr[NN] = NE;
}

__global__ void k_scatter(const int* __restrict__ row, const int* __restrict__ col,
                          const int* __restrict__ indptr,
                          int* __restrict__ fill, int* __restrict__ esrc) {
    int e = blockIdx.x * 256 + threadIdx.x;
    if (e >= NE) return;
    int r = row[e], c = col[e];
    int pos = indptr[c] + atomicAdd(&fill[c], 1);
    esrc[pos] = r;
}

// batch is sorted: graph starts via boundary detection (no atomics, no scan)
__global__ void k_gbounds(const int* __restrict__ batch, int* __restrict__ gstart) {
    int i = blockIdx.x * 256 + threadIdx.x;
    if (i >= NN) return;
    int b = batch[i];
    int pb = (i == 0) ? -1 : batch[i - 1];
    for (int g = pb + 1; g <= b; g++) gstart[g] = i;
    if (i == NN - 1) {
        for (int g = b + 1; g <= NG; g++) gstart[g] = NN;
    }
}

// ----- all 5 weight conversions in one launch: Wt_{hi,lo}[112][KCP], zero-padded -----
__global__ void k_convWall(const float* __restrict__ W1, unsigned short* __restrict__ w1h, unsigned short* __restrict__ w1l,
                           const float* __restrict__ W2, unsigned short* __restrict__ w2h, unsigned short* __restrict__ w2l,
                           const float* __restrict__ W3, unsigned short* __restrict__ w3h, unsigned short* __restrict__ w3l,
                           const float* __restrict__ W4, unsigned short* __restrict__ w4h, unsigned short* __restrict__ w4l,
                           const float* __restrict__ W5, unsigned short* __restrict__ w5h, unsigned short* __restrict__ w5l) {
    int b = blockIdx.x, t = threadIdx.x;
    const float* W; unsigned short *Wh, *Wl; int K, KCP, idx;
    if (b < 168) {            // layer 1: 112*384 = 43008 = 168 blocks
        W = W1; Wh = w1h; Wl = w1l; K = 336; KCP = 384; idx = b * 256 + t;
    } else {                  // layers 2..5: 112*128 = 14336 = 56 blocks each
        int li = (b - 168) / 56;
        int lb = (b - 168) % 56;
        const float* Ws[4] = {W2, W3, W4, W5};
        unsigned short* Whs[4] = {w2h, w3h, w4h, w5h};
        unsigned short* Wls[4] = {w2l, w3l, w4l, w5l};
        W = Ws[li]; Wh = Whs[li]; Wl = Wls[li]; K = 100; KCP = 128; idx = lb * 256 + t;
    }
    int n = idx / KCP, k = idx - n * KCP;
    float v = (n < 100 && k < K) ? W[k * 100 + n] : 0.f;
    unsigned short hi = f2bf(v);
    Wh[idx] = hi;
    Wl[idx] = f2bf(v - bf2f(hi));
}

// ---- split-bf16 MFMA GEMM (fp32 A input, layer 1): xsh = fp16(dinv * (A @ W)) ----
__global__ __launch_bounds__(256) void k_gemm3(const float* __restrict__ A,
                                               const unsigned short* __restrict__ Wthi,
                                               const unsigned short* __restrict__ Wtlo,
                                               const float* __restrict__ dinv,
                                               __half* __restrict__ out,
                                               int M, int K, int KCP, int lda) {
    __shared__ float As[64 * 68];
    __shared__ __align__(16) unsigned short Hs[112 * 72];
    __shared__ __align__(16) unsigned short Ls[112 * 72];
    int t = threadIdx.x;
    int lane = t & 63;
    int wv = t >> 6;
    int l15 = lane & 15, quad = lane >> 4;
    int rowbase = blockIdx.x * 64;

    f32x4 acc[7];
#pragma unroll
    for (int i = 0; i < 7; i++)
#pragma unroll
        for (int r = 0; r < 4; r++) acc[i][r] = 0.f;

    for (int k0 = 0; k0 < KCP; k0 += 64) {
        __syncthreads();
#pragma unroll
        for (int j = 0; j < 4; j++) {
            int e = t + j * 256;
            int r = e >> 4;
            int c4 = (e & 15) * 4;
            int gr = rowbase + r, gk = k0 + c4;
            float4 v = make_float4(0.f, 0.f, 0.f, 0.f);
            if (gr < M && gk < K) v = *(const float4*)(A + (size_t)gr * lda + gk);
            *(float4*)(&As[r * 68 + c4]) = v;
        }
#pragma unroll
        for (int j = 0; j < 7; j++) {
            int e = t + j * 256;
            int n = e >> 4;
            int c = (e & 15) * 4;
            size_t g = (size_t)n * KCP + k0 + c;
            *(uint2*)(&Hs[n * 72 + c]) = *(const uint2*)(Wthi + g);
            *(uint2*)(&Ls[n * 72 + c]) = *(const uint2*)(Wtlo + g);
        }
        __syncthreads();
#pragma unroll
        for (int ks = 0; ks < 2; ks++) {
            int arow = wv * 16 + l15;
            const float* ap = &As[arow * 68 + ks * 32 + quad * 8];
            float4 a0 = *(const float4*)ap;
            float4 a1 = *(const float4*)(ap + 4);
            float af[8] = {a0.x, a0.y, a0.z, a0.w, a1.x, a1.y, a1.z, a1.w};
            s16x8 ahi, alo;
#pragma unroll
            for (int j = 0; j < 8; j++) {
                unsigned short h = f2bf(af[j]);
                ahi[j] = (short)h;
                alo[j] = (short)f2bf(af[j] - bf2f(h));
            }
            int koff = ks * 32 + quad * 8;
#pragma unroll
            for (int tt = 0; tt < 7; tt++) {
                int nrow = tt * 16 + l15;
                s16x8 bhi = *(const s16x8*)(&Hs[nrow * 72 + koff]);
                s16x8 blo = *(const s16x8*)(&Ls[nrow * 72 + koff]);
                acc[tt] = __builtin_amdgcn_mfma_f32_16x16x32_bf16(ahi, bhi, acc[tt], 0, 0, 0);
                acc[tt] = __builtin_amdgcn_mfma_f32_16x16x32_bf16(ahi, blo, acc[tt], 0, 0, 0);
                acc[tt] = __builtin_amdgcn_mfma_f32_16x16x32_bf16(alo, bhi, acc[tt], 0, 0, 0);
            }
        }
    }

    int gr0 = rowbase + wv * 16 + quad * 4;
    float dv[4];
#pragma unroll
    for (int reg = 0; reg < 4; reg++) dv[reg] = (gr0 + reg < M) ? dinv[gr0 + reg] : 0.f;
#pragma unroll
    for (int tt = 0; tt < 7; tt++) {
        int n = tt * 16 + l15;
#pragma unroll
        for (int reg = 0; reg < 4; reg++) {
            int gr = gr0 + reg;
            if (gr < M) out[(size_t)gr * LDX + n] = __float2half(dv[reg] * acc[tt][reg]);
        }
    }
}

// ---- split-bf16 MFMA GEMM (split-bf16 A tables, layers 2-5): xsh = fp16(dinv*(h @ W)) ----
__global__ __launch_bounds__(256) void k_gemm3s(const unsigned short* __restrict__ hhi,
                                                const unsigned short* __restrict__ hlo,
                                                const unsigned short* __restrict__ Wthi,
                                                const unsigned short* __restrict__ Wtlo,
                                                const float* __restrict__ dinv,
                                                __half* __restrict__ out) {
    __shared__ __align__(16) unsigned short Ahi[64 * 72];
    __shared__ __align__(16) unsigned short Alo[64 * 72];
    __shared__ __align__(16) unsigned short Hs[112 * 72];
    __shared__ __align__(16) unsigned short Ls[112 * 72];
    int t = threadIdx.x;
    int lane = t & 63;
    int wv = t >> 6;
    int l15 = lane & 15, quad = lane >> 4;
    int rowbase = blockIdx.x * 64;

    f32x4 acc[7];
#pragma unroll
    for (int i = 0; i < 7; i++)
#pragma unroll
        for (int r = 0; r < 4; r++) acc[i][r] = 0.f;

    for (int k0 = 0; k0 < 128; k0 += 64) {
        __syncthreads();
#pragma unroll
        for (int j = 0; j < 2; j++) {
            int e = t + j * 256;           // 0..511
            int r = e >> 3;                // 0..63
            int c8 = (e & 7) * 8;          // 0..56
            int gr = rowbase + r;
            int gk = k0 + c8;
            uint4 vh = make_uint4(0, 0, 0, 0), vl = vh;
            if (gr < NN && gk + 8 <= LDH) {
                size_t g = (size_t)gr * LDH + gk;
                vh = *(const uint4*)(hhi + g);
                vl = *(const uint4*)(hlo + g);
            }
            *(uint4*)(&Ahi[r * 72 + c8]) = vh;
            *(uint4*)(&Alo[r * 72 + c8]) = vl;
        }
#pragma unroll
        for (int j = 0; j < 7; j++) {
            int e = t + j * 256;
            int n = e >> 4;
            int c = (e & 15) * 4;
            size_t g = (size_t)n * 128 + k0 + c;
            *(uint2*)(&Hs[n * 72 + c]) = *(const uint2*)(Wthi + g);
            *(uint2*)(&Ls[n * 72 + c]) = *(const uint2*)(Wtlo + g);
        }
        __syncthreads();
#pragma unroll
        for (int ks = 0; ks < 2; ks++) {
            int arow = wv * 16 + l15;
            int koff = ks * 32 + quad * 8;
            s16x8 ahi = *(const s16x8*)(&Ahi[arow * 72 + koff]);
            s16x8 alo = *(const s16x8*)(&Alo[arow * 72 + koff]);
#pragma unroll
            for (int tt = 0; tt < 7; tt++) {
                int nrow = tt * 16 + l15;
                s16x8 bhi = *(const s16x8*)(&Hs[nrow * 72 + koff]);
                s16x8 blo = *(const s16x8*)(&Ls[nrow * 72 + koff]);
                acc[tt] = __builtin_amdgcn_mfma_f32_16x16x32_bf16(ahi, bhi, acc[tt], 0, 0, 0);
                acc[tt] = __builtin_amdgcn_mfma_f32_16x16x32_bf16(ahi, blo, acc[tt], 0, 0, 0);
                acc[tt] = __builtin_amdgcn_mfma_f32_16x16x32_bf16(alo, bhi, acc[tt], 0, 0, 0);
            }
        }
    }

    int gr0 = rowbase + wv * 16 + quad * 4;
    float dv[4];
#pragma unroll
    for (int reg = 0; reg < 4; reg++) dv[reg] = (gr0 + reg < NN) ? dinv[gr0 + reg] : 0.f;
#pragma unroll
    for (int tt = 0; tt < 7; tt++) {
        int n = tt * 16 + l15;
#pragma unroll
        for (int reg = 0; reg < 4; reg++) {
            int gr = gr0 + reg;
            if (gr < NN) out[(size_t)gr * LDX + n] = __float2half(dv[reg] * acc[tt][reg]);
        }
    }
}

// ---- aggregation core: gathers fp16 rows (4 cache lines/row), fp32 accumulate ----
__device__ __forceinline__ void agg_core(const __half* __restrict__ xs,
                                         const int* __restrict__ esrc,
                                         int beg, int end, int lane, int col,
                                         float& ax, float& ay) {
    ax = 0.f; ay = 0.f;
    for (int c = beg; c < end; c += 64) {
        int m = min(64, end - c);
        int se = 0;
        if (lane < m) se = esrc[c + lane];
        int j = 0;
        for (; j + 16 <= m; j += 16) {
            __half2 v[16];
#pragma unroll
            for (int u = 0; u < 16; u++) {
                int s = __builtin_amdgcn_readlane(se, j + u);
                v[u] = *(const __half2*)(xs + (size_t)s * LDX + col);
            }
#pragma unroll
            for (int u = 0; u < 16; u++) {
                float2 f = __half22float2(v[u]);
                ax += f.x; ay += f.y;
            }
        }
        for (; j + 8 <= m; j += 8) {
            __half2 v[8];
#pragma unroll
            for (int u = 0; u < 8; u++) {
                int s = __builtin_amdgcn_readlane(se, j + u);
                v[u] = *(const __half2*)(xs + (size_t)s * LDX + col);
            }
#pragma unroll
            for (int u = 0; u < 8; u++) {
                float2 f = __half22float2(v[u]);
                ax += f.x; ay += f.y;
            }
        }
        for (; j + 4 <= m; j += 4) {
            __half2 v[4];
#pragma unroll
            for (int u = 0; u < 4; u++) {
                int s = __builtin_amdgcn_readlane(se, j + u);
                v[u] = *(const __half2*)(xs + (size_t)s * LDX + col);
            }
#pragma unroll
            for (int u = 0; u < 4; u++) {
                float2 f = __half22float2(v[u]);
                ax += f.x; ay += f.y;
            }
        }
        for (; j < m; j++) {
            int s = __builtin_amdgcn_readlane(se, j);
            float2 f = __half22float2(*(const __half2*)(xs + (size_t)s * LDX + col));
            ax += f.x; ay += f.y;
        }
    }
}

// ---- agg with split-bf16 epilogue (layers 1-4): writes hhi/hlo tables ----
__global__ __launch_bounds__(256) void k_aggS(const __half* __restrict__ xs,
                                              const int* __restrict__ indptr,
                                              const int* __restrict__ esrc,
                                              const float* __restrict__ dinv,
                                              const float* __restrict__ bias,
                                              unsigned short* __restrict__ hhi,
                                              unsigned short* __restrict__ hlo) {
    int wave = threadIdx.x >> 6;
    int lane = threadIdx.x & 63;
    int n = blockIdx.x * 4 + wave;
    if (n >= NN) return;
    int beg = indptr[n], end = indptr[n + 1];
    int col = (lane < 50) ? lane * 2 : 0;
    float ax, ay;
    agg_core(xs, esrc, beg, end, lane, col, ax, ay);
    if (lane < 50) {
        float di = dinv[n];
        float2 xv = __half22float2(*(const __half2*)(xs + (size_t)n * LDX + col));
        float2 bv = *(const float2*)(bias + lane * 2);
        float hx = fmaxf(di * (ax + 2.f * xv.x) + bv.x, 0.f);
        float hy = fmaxf(di * (ay + 2.f * xv.y) + bv.y, 0.f);
        unsigned short xh = f2bf(hx), yh = f2bf(hy);
        *(ushort2*)(hhi + (size_t)n * LDH + col) = make_ushort2(xh, yh);
        *(ushort2*)(hlo + (size_t)n * LDH + col) =
            make_ushort2(f2bf(hx - bf2f(xh)), f2bf(hy - bf2f(yh)));
    } else if (lane < 56) {
        int pc = 100 + (lane - 50) * 2;
        *(ushort2*)(hhi + (size_t)n * LDH + pc) = make_ushort2(0, 0);
        *(ushort2*)(hlo + (size_t)n * LDH + pc) = make_ushort2(0, 0);
    }
}

// ---- agg with fp32 epilogue (layer 5): writes h for pooling ----
__global__ __launch_bounds__(256) void k_agg(const __half* __restrict__ xs,
                                             const int* __restrict__ indptr,
                                             const int* __restrict__ esrc,
                                             const float* __restrict__ dinv,
                                             const float* __restrict__ bias,
                                             float* __restrict__ hout) {
    int wave = threadIdx.x >> 6;
    int lane = threadIdx.x & 63;
    int n = blockIdx.x * 4 + wave;
    if (n >= NN) return;
    int beg = indptr[n], end = indptr[n + 1];
    int col = (lane < 50) ? lane * 2 : 0;
    float ax, ay;
    agg_core(xs, esrc, beg, end, lane, col, ax, ay);
    if (lane < 50) {
        float di = dinv[n];
        float2 xv = __half22float2(*(const __half2*)(xs + (size_t)n * LDX + col));
        float2 bv = *(const float2*)(bias + lane * 2);
        float2 r;
        r.x = fmaxf(di * (ax + 2.f * xv.x) + bv.x, 0.f);
        r.y = fmaxf(di * (ay + 2.f * xv.y) + bv.y, 0.f);
        *(float2*)(hout + (size_t)n * LDA + col) = r;
    }
}

// ---------------- pooling (8-way ILP over nodes) ----------------
__global__ __launch_bounds__(128) void k_pool(const float* __restrict__ h,
                                              const int* __restrict__ gstart,
                                              float* __restrict__ pooled) {
    int g = blockIdx.x, t = threadIdx.x;
    if (t >= 100) return;
    int st = gstart[g];
    int cnt = gstart[g + 1] - st;
    float s0 = 0.f, s1 = 0.f, s2 = 0.f, s3 = 0.f;
    float s4 = 0.f, s5 = 0.f, s6 = 0.f, s7 = 0.f;
    int i = 0;
    for (; i + 8 <= cnt; i += 8) {
        s0 += h[(size_t)(st + i) * LDA + t];
        s1 += h[(size_t)(st + i + 1) * LDA + t];
        s2 += h[(size_t)(st + i + 2) * LDA + t];
        s3 += h[(size_t)(st + i + 3) * LDA + t];
        s4 += h[(size_t)(st + i + 4) * LDA + t];
        s5 += h[(size_t)(st + i + 5) * LDA + t];
        s6 += h[(size_t)(st + i + 6) * LDA + t];
        s7 += h[(size_t)(st + i + 7) * LDA + t];
    }
    for (; i < cnt; i++) s0 += h[(size_t)(st + i) * LDA + t];
    float s = ((s0 + s1) + (s2 + s3)) + ((s4 + s5) + (s6 + s7));
    pooled[g * 100 + t] = s / (float)(cnt > 0 ? cnt : 1);
}

// ---------------- MLP head (fused 3 layers, one block per graph) ----------------
__global__ void k_mlp(const float* __restrict__ pooled,
                      const float* __restrict__ Wl1, const float* __restrict__ bl1,
                      const float* __restrict__ Wl2, const float* __restrict__ bl2,
                      const float* __restrict__ Wl3, const float* __restrict__ bl3,
                      float* __restrict__ out) {
    __shared__ float p[100], q[100];
    int g = blockIdx.x, t = threadIdx.x;
    if (t < 100) p[t] = pooled[g * 100 + t];
    __syncthreads();
    float s1 = 0.f;
    if (t < 100) {
        s1 = bl1[t];
        for (int k = 0; k < 100; k++) s1 += p[k] * Wl1[k * 100 + t];
        s1 = fmaxf(s1, 0.f);
    }
    __syncthreads();
    if (t < 100) q[t] = s1;
    __syncthreads();
    float s2 = 0.f;
    if (t < 100) {
        s2 = bl2[t];
        for (int k = 0; k < 100; k++) s2 += q[k] * Wl2[k * 100 + t];
        s2 = fmaxf(s2, 0.f);
    }
    __syncthreads();
    if (t < 100) p[t] = s2;
    __syncthreads();
    if (t < 29) {
        float s3 = bl3[t];
        for (int k = 0; k < 100; k++) s3 += p[k] * Wl3[k * 29 + t];
        out[g * 29 + t] = s3;
    }
}

// ---------------- launch ----------------
extern "C" void kernel_launch(void* const* d_in, const int* in_sizes, int n_in,
                              void* d_out, int out_size, void* d_ws, size_t ws_size,
                              hipStream_t stream) {
    const float* x     = (const float*)d_in[0];
    const int*   ei    = (const int*)d_in[1];
    const int*   batch = (const int*)d_in[2];
    const float* W1 = (const float*)d_in[3];  const float* b1 = (const float*)d_in[4];
    const float* W2 = (const float*)d_in[5];  const float* b2 = (const float*)d_in[6];
    const float* W3 = (const float*)d_in[7];  const float* b3 = (const float*)d_in[8];
    const float* W4 = (const float*)d_in[9];  const float* b4 = (const float*)d_in[10];
    const float* W5 = (const float*)d_in[11]; const float* b5 = (const float*)d_in[12];
    const float* Wl1 = (const float*)d_in[13]; const float* bl1 = (const float*)d_in[14];
    const float* Wl2 = (const float*)d_in[15]; const float* bl2 = (const float*)d_in[16];
    const float* Wl3 = (const float*)d_in[17]; const float* bl3 = (const float*)d_in[18];
    float* out = (float*)d_out;

    const int* row = ei;
    const int* col = ei + NE;

    uintptr_t base = (uintptr_t)d_ws;
    auto alloc = [&](size_t bytes) -> void* {
        void* p = (void*)base;
        base += (bytes + 255) & ~(size_t)255;
        return p;
    };
    // contiguous atomic-counter region -> single memset
    int*   cnts   = (int*)alloc((size_t)(2 * NN) * 4);
    int*   degcnt = cnts;
    int*   fill   = cnts + NN;
    float* dinv   = (float*)alloc(NN * 4);
    int*   indptr = (int*)alloc((NN + 1) * 4);
    int*   csum   = (int*)alloc(512 * 4);
    int*   csum2  = (int*)alloc(512 * 4);
    int*   gstart = (int*)alloc((NG + 1) * 4);
    int*   esrc   = (int*)alloc((size_t)NE * 4);
    __half* xsh   = (__half*)alloc((size_t)NN * LDX * 2);
    float* h      = (float*)alloc((size_t)NN * LDA * 4);
    unsigned short* hhi = (unsigned short*)alloc((size_t)NN * LDH * 2);
    unsigned short* hlo = (unsigned short*)alloc((size_t)NN * LDH * 2);
    float* pooled = (float*)alloc((size_t)NG * 100 * 4);
    unsigned short* w1hi = (unsigned short*)alloc((size_t)112 * 384 * 2);
    unsigned short* w1lo = (unsigned short*)alloc((size_t)112 * 384 * 2);
    unsigned short* w2hi = (unsigned short*)alloc((size_t)112 * 128 * 2);
    unsigned short* w2lo = (unsigned short*)alloc((size_t)112 * 128 * 2);
    unsigned short* w3hi = (unsigned short*)alloc((size_t)112 * 128 * 2);
    unsigned short* w3lo = (unsigned short*)alloc((size_t)112 * 128 * 2);
    unsigned short* w4hi = (unsigned short*)alloc((size_t)112 * 128 * 2);
    unsigned short* w4lo = (unsigned short*)alloc((size_t)112 * 128 * 2);
    unsigned short* w5hi = (unsigned short*)alloc((size_t)112 * 128 * 2);
    unsigned short* w5lo = (unsigned short*)alloc((size_t)112 * 128 * 2);

    hipMemsetAsync(cnts, 0, (size_t)(2 * NN) * 4, stream);

    const int NB = (NN + 255) / 256;  // 391
    k_deg<<<(NE + 255) / 256, 256, 0, stream>>>(col, degcnt);
    k_scan1<<<NB, 256, 0, stream>>>(degcnt, csum);
    k_scan2<<<1, 512, 0, stream>>>(csum, csum2, NB);
    k_scan3d<<<NB, 256, 0, stream>>>(degcnt, csum2, indptr, dinv);
    k_scatter<<<(NE + 255) / 256, 256, 0, stream>>>(row, col, indptr, fill, esrc);
    k_gbounds<<<NB, 256, 0, stream>>>(batch, gstart);
    k_convWall<<<392, 256, 0, stream>>>(W1, w1hi, w1lo, W2, w2hi, w2lo,
                                        W3, w3hi, w3lo, W4, w4hi, w4lo,
                                        W5, w5hi, w5lo);

    const int GEMM_GRID = (NN + 63) / 64;  // 1563
    const int AGG_GRID = (NN + 3) / 4;     // 25000

    k_gemm3<<<GEMM_GRID, 256, 0, stream>>>(x, w1hi, w1lo, dinv, xsh, NN, 336, 384, 336);
    k_aggS<<<AGG_GRID, 256, 0, stream>>>(xsh, indptr, esrc, dinv, b1, hhi, hlo);
    k_gemm3s<<<GEMM_GRID, 256, 0, stream>>>(hhi, hlo, w2hi, w2lo, dinv, xsh);
    k_aggS<<<AGG_GRID, 256, 0, stream>>>(xsh, indptr, esrc, dinv, b2, hhi, hlo);
    k_gemm3s<<<GEMM_GRID, 256, 0, stream>>>(hhi, hlo, w3hi, w3lo, dinv, xsh);
    k_aggS<<<AGG_GRID, 256, 0, stream>>>(xsh, indptr, esrc, dinv, b3, hhi, hlo);
    k_gemm3s<<<GEMM_GRID, 256, 0, stream>>>(hhi, hlo, w4hi, w4lo, dinv, xsh);
    k_aggS<<<AGG_GRID, 256, 0, stream>>>(xsh, indptr, esrc, dinv, b4, hhi, hlo);
    k_gemm3s<<<GEMM_GRID, 256, 0, stream>>>(hhi, hlo, w5hi, w5lo, dinv, xsh);
    k_agg<<<AGG_GRID, 256, 0, stream>>>(xsh, indptr, esrc, dinv, b5, h);

    k_pool<<<NG, 128, 0, stream>>>(h, gstart, pooled);
    k_mlp<<<NG, 128, 0, stream>>>(pooled, Wl1, bl1, Wl2, bl2, Wl3, bl3, out);
}